// Round 1
// baseline (83.146 us; speedup 1.0000x reference)
//
#include <hip/hip_runtime.h>

// Problem constants (from reference): BS=8, Q=500, NC=2, T=400
#define P_TOT 4000   // BS*Q
#define T_TOT 400
#define PP    8      // preds per block
#define BD    448    // 7 waves; covers all 400 targets, 10.7% lane waste
#define CROWS 112    // target rows staged per LDS chunk (4 chunks cover 448)
#define CFLOATS (CROWS * 53)   // 5936 floats = 23744 B LDS

__global__ __launch_bounds__(BD, 3) void hm_cost_kernel(
    const float* __restrict__ logits,    // [P_TOT, 2]
    const float* __restrict__ kp,        // [P_TOT, 53]
    const int*   __restrict__ tgt_ids,   // [T_TOT]
    const float* __restrict__ tk,        // [T_TOT, 53]
    const int*   __restrict__ num_boxes, // [1]
    float*       __restrict__ out)       // [P_TOT, T_TOT]
{
    // LDS transpose buffer: coalesced global loads in, per-lane row reads out.
    // Row stride 53 is odd (53 % 32 = 21) -> per-lane LDS gather is
    // bank-conflict-free (only the free 2-way wave64 aliasing, m136).
    __shared__ float smem[CFLOATS];

    const int t      = threadIdx.x;
    const bool valid = (t < T_TOT);
    const int tc     = valid ? t : (T_TOT - 1);   // clamp for safe loads

    const float nbinv = 1.0f / (float)(*num_boxes);
    const bool  cls1  = (tgt_ids[tc] != 0);

    // ---- stage tgt table via LDS (4 chunks x 112 rows), pin row in regs ----
    float Cg0 = 0.f, Cg1 = 0.f, sVg = 0.f;
    float Zg[34];
    float Vg[17];

#pragma unroll
    for (int c = 0; c < 4; ++c) {
        const int row0 = c * CROWS;
        const int rows = (row0 + CROWS <= T_TOT) ? CROWS : (T_TOT - row0); // 112,112,112,64
        const int nf4  = (rows * 53) >> 2;        // rows%4==0 -> exact float4 count
        // coalesced copy: chunk base = row0*53*4 B, always 16B-aligned
        const float4* __restrict__ src = (const float4*)(tk + row0 * 53);
        float4* dst = (float4*)smem;
        for (int i = t; i < nf4; i += BD) dst[i] = src[i];
        __syncthreads();
        if (tc >= row0 && tc < row0 + rows) {
            const float* r = smem + (tc - row0) * 53;
            Cg0 = r[0];
            Cg1 = r[1];
#pragma unroll
            for (int k = 0; k < 34; ++k) Zg[k] = r[2 + k];
            sVg = 0.f;
#pragma unroll
            for (int j = 0; j < 17; ++j) {
                const float v = r[36 + j];
                Vg[j] = v;
                sVg += v * v;
            }
        }
        __syncthreads();   // protect smem before next chunk overwrites
    }

    const int pbase = blockIdx.x * PP;

#pragma unroll 1
    for (int pi = 0; pi < PP; ++pi) {
        const int p = pbase + pi;                 // uniform across block
        const float* prow = kp + p * 53;          // uniform address (broadcast)

        // 2-class softmax with one exp: p0 = 1/(1+e^(l1-l0)), p1 = q*p0
        const float l0 = logits[2 * p];
        const float l1 = logits[2 * p + 1];
        const float q  = __expf(l1 - l0);
        const float p0 = 1.0f / (1.0f + q);
        const float prob = cls1 ? (q * p0) : p0;

        const float dc0 = prow[0] - Cg0;
        const float dc1 = prow[1] - Cg1;

        // fused 17-iter loop: offset L1, abs L1 (shares dz), vis cross-term.
        // Vg in {0,1} >= 0, so |dz*v| == |dz|*v.
        float off = 0.f, ab = 0.f, vv = 0.f, sVp = 0.f;
#pragma unroll
        for (int j = 0; j < 17; ++j) {
            const float v   = Vg[j];
            const float zp0 = prow[2 + 2 * j];
            const float zp1 = prow[3 + 2 * j];
            const float dz0 = zp0 - Zg[2 * j];
            const float dz1 = zp1 - Zg[2 * j + 1];
            off += (fabsf(dz0) + fabsf(dz1)) * v;
            ab  += (fabsf(dz0 + dc0) + fabsf(dz1 + dc1)) * v;
            const float vp = prow[36 + j];
            vv  += vp * v;
            sVp += vp * vp;
        }

        const float viz = sVp - 2.f * vv + sVg;   // sum (Vp - Vg)^2
        const float ctr = dc0 * dc0 + dc1 * dc1;

        const float cst = -prob
                        + (0.5f * off + 4.0f * ab + 0.2f * viz + 0.5f * ctr) * nbinv;

        if (valid) out[p * T_TOT + t] = cst;      // coalesced, t-contiguous
    }
}

extern "C" void kernel_launch(void* const* d_in, const int* in_sizes, int n_in,
                              void* d_out, int out_size, void* d_ws, size_t ws_size,
                              hipStream_t stream) {
    const float* logits    = (const float*)d_in[0];  // pred_logits    [8,500,2]
    const float* kp        = (const float*)d_in[1];  // pred_keypoints [8,500,53]
    const int*   tgt_ids   = (const int*)  d_in[2];  // [400]
    const float* tk        = (const float*)d_in[3];  // tgt_keypoints  [400,53]
    const int*   num_boxes = (const int*)  d_in[4];  // scalar
    float*       out       = (float*)d_out;          // [8,500,400] fp32

    hm_cost_kernel<<<P_TOT / PP, BD, 0, stream>>>(logits, kp, tgt_ids, tk,
                                                  num_boxes, out);
}

// Round 2
// 79.572 us; speedup vs baseline: 1.0449x; 1.0449x over previous
//
#include <hip/hip_runtime.h>

// Problem constants (from reference): BS=8, Q=500, NC=2, T=400
#define P_TOT 4000   // BS*Q
#define T_TOT 400
#define PP    8      // preds per block
#define BD    448    // 7 waves; covers all 400 targets, 10.7% lane waste
#define PROWF 56     // padded pred-row stride in LDS floats (224 B, 16B-aligned)

__global__ __launch_bounds__(BD, 3) void hm_cost_kernel(
    const float* __restrict__ logits,    // [P_TOT, 2]
    const float* __restrict__ kp,        // [P_TOT, 53]
    const int*   __restrict__ tgt_ids,   // [T_TOT]
    const float* __restrict__ tk,        // [T_TOT, 53]
    const int*   __restrict__ num_boxes, // [1]
    float*       __restrict__ out)       // [P_TOT, T_TOT]
{
    // Pred rows for this block staged ONCE, padded to 56 floats so every
    // float2 read below is 8B-aligned. All main-loop reads of pred data are
    // same-address LDS broadcasts (free). Target rows stay register-pinned
    // via the direct gather (proven faster than LDS-chunked staging in R1).
    __shared__ float sp[PP * PROWF];   // 8 x 56 floats = 1.75 KB
    __shared__ float sl[PP * 2];       // 16 logits

    const int t      = threadIdx.x;
    const bool valid = (t < T_TOT);
    const int tc     = valid ? t : (T_TOT - 1);   // clamp for safe loads
    const int pbase  = blockIdx.x * PP;

    // ---- stage this block's 8 pred rows + logits (coalesced dword loads) ----
    if (t < PP * 53) {                    // 424 contiguous floats from global
        const float v = kp[pbase * 53 + t];
        const int r = t / 53;             // compiler: magic-mul
        const int c = t - r * 53;
        sp[r * PROWF + c] = v;
    }
    if (t < PP * 2) sl[t] = logits[pbase * 2 + t];

    const float nbinv = 1.0f / (float)(*num_boxes);

    // ---- pin this thread's target row in registers (divergent, once) ----
    const float* trow = tk + tc * 53;
    const float Cg0 = trow[0];
    const float Cg1 = trow[1];
    float Zg[34];
#pragma unroll
    for (int k = 0; k < 34; ++k) Zg[k] = trow[2 + k];
    float Vg[17];
    float sVg = 0.f;
#pragma unroll
    for (int j = 0; j < 17; ++j) {
        Vg[j] = trow[36 + j];
        sVg += Vg[j] * Vg[j];
    }
    const bool cls1 = (tgt_ids[tc] != 0);

    __syncthreads();

    const float wo = 0.5f * nbinv;
    const float wa = 4.0f * nbinv;
    const float wv = 0.2f * nbinv;
    const float wc = 0.5f * nbinv;

#pragma unroll 1
    for (int pi = 0; pi < PP; ++pi) {
        const float* __restrict__ r = sp + pi * PROWF;   // LDS, broadcast reads

        // 2-class softmax with one exp: p0 = 1/(1+e^(l1-l0)), p1 = q*p0
        const float l0 = sl[2 * pi];
        const float l1 = sl[2 * pi + 1];
        const float q  = __expf(l1 - l0);
        const float p0 = 1.0f / (1.0f + q);
        const float prob = cls1 ? (q * p0) : p0;

        const float2 cpr = *(const float2*)(r);          // 224B-mult base: 8B ok
        const float dc0 = cpr.x - Cg0;
        const float dc1 = cpr.y - Cg1;

        // fused 17-iter loop: offset L1, abs L1 (shares dz), vis cross-term.
        // Vg in {0,1} >= 0, so |dz*v| == |dz|*v.
        float off = 0.f, ab = 0.f, vv = 0.f, sVp = 0.f;
#pragma unroll
        for (int j = 0; j < 17; ++j) {
            const float v   = Vg[j];
            const float2 zp = *(const float2*)(r + 2 + 2 * j);  // (8+8j)B: 8B ok
            const float dz0 = zp.x - Zg[2 * j];
            const float dz1 = zp.y - Zg[2 * j + 1];
            off += (fabsf(dz0) + fabsf(dz1)) * v;
            ab  += (fabsf(dz0 + dc0) + fabsf(dz1 + dc1)) * v;
            const float vp = r[36 + j];
            vv  += vp * v;
            sVp += vp * vp;
        }

        const float viz = sVp - 2.f * vv + sVg;   // sum (Vp - Vg)^2
        const float ctr = dc0 * dc0 + dc1 * dc1;

        const float cst = fmaf(off, wo,
                          fmaf(ab, wa,
                          fmaf(viz, wv,
                          fmaf(ctr, wc, -prob))));

        if (valid) out[(pbase + pi) * T_TOT + t] = cst;   // coalesced
    }
}

extern "C" void kernel_launch(void* const* d_in, const int* in_sizes, int n_in,
                              void* d_out, int out_size, void* d_ws, size_t ws_size,
                              hipStream_t stream) {
    const float* logits    = (const float*)d_in[0];  // pred_logits    [8,500,2]
    const float* kp        = (const float*)d_in[1];  // pred_keypoints [8,500,53]
    const int*   tgt_ids   = (const int*)  d_in[2];  // [400]
    const float* tk        = (const float*)d_in[3];  // tgt_keypoints  [400,53]
    const int*   num_boxes = (const int*)  d_in[4];  // scalar
    float*       out       = (float*)d_out;          // [8,500,400] fp32

    hm_cost_kernel<<<P_TOT / PP, BD, 0, stream>>>(logits, kp, tgt_ids, tk,
                                                  num_boxes, out);
}

// Round 3
// 78.310 us; speedup vs baseline: 1.0618x; 1.0161x over previous
//
#include <hip/hip_runtime.h>

// Problem constants (from reference): BS=8, Q=500, NC=2, T=400
#define P_TOT 4000   // BS*Q
#define T_TOT 400
#define PP    8      // preds per block
#define BD    448    // 7 waves; covers all 400 targets, 10.7% lane waste

// R3 = exact revert to the R0/prev-session best (78.1/78.4 us).
// R1 (LDS target staging) = +4.7us, R2 (LDS pred staging) = +1.2us: both
// "fixes" regressed because the main-loop pred reads are uniform-address
// scalar loads (free) and the kernel itself is ~3-6us against a ~74us
// harness fixture floor (one 40us 256MiB poison fill + dozens of tiny
// reset dispatches). This revert is the decisive test of that model.
__global__ __launch_bounds__(BD, 3) void hm_cost_kernel(
    const float* __restrict__ logits,    // [P_TOT, 2]
    const float* __restrict__ kp,        // [P_TOT, 53]
    const int*   __restrict__ tgt_ids,   // [T_TOT]
    const float* __restrict__ tk,        // [T_TOT, 53]
    const int*   __restrict__ num_boxes, // [1]
    float*       __restrict__ out)       // [P_TOT, T_TOT]
{
    const int t      = threadIdx.x;
    const bool valid = (t < T_TOT);
    const int tc     = valid ? t : (T_TOT - 1);   // clamp for safe loads

    const float nbinv = 1.0f / (float)(*num_boxes);

    // ---- pin this thread's target row in registers for the whole block ----
    const float* trow = tk + tc * 53;
    const float Cg0 = trow[0];
    const float Cg1 = trow[1];
    float Zg[34];
#pragma unroll
    for (int k = 0; k < 34; ++k) Zg[k] = trow[2 + k];
    float Vg[17];
    float sVg = 0.f;   // sum Vg^2 (hoisted out of pred loop)
#pragma unroll
    for (int j = 0; j < 17; ++j) {
        Vg[j] = trow[36 + j];
        sVg += Vg[j] * Vg[j];
    }
    const bool cls1 = (tgt_ids[tc] != 0);

    const int pbase = blockIdx.x * PP;

#pragma unroll 1
    for (int pi = 0; pi < PP; ++pi) {
        const int p = pbase + pi;                 // uniform across block
        const float* prow = kp + p * 53;          // uniform address -> s_load

        // 2-class softmax with one exp: p0 = 1/(1+e^(l1-l0)), p1 = q*p0
        const float l0 = logits[2 * p];
        const float l1 = logits[2 * p + 1];
        const float q  = __expf(l1 - l0);
        const float p0 = 1.0f / (1.0f + q);
        const float prob = cls1 ? (q * p0) : p0;

        const float dc0 = prow[0] - Cg0;
        const float dc1 = prow[1] - Cg1;

        // fused 17-iter loop: offset L1, abs L1 (shares dz), vis cross-term.
        // Vg in {0,1} >= 0, so |dz*v| == |dz|*v.
        float off = 0.f, ab = 0.f, vv = 0.f, sVp = 0.f;
#pragma unroll
        for (int j = 0; j < 17; ++j) {
            const float v   = Vg[j];
            const float zp0 = prow[2 + 2 * j];
            const float zp1 = prow[3 + 2 * j];
            const float dz0 = zp0 - Zg[2 * j];
            const float dz1 = zp1 - Zg[2 * j + 1];
            off += (fabsf(dz0) + fabsf(dz1)) * v;
            ab  += (fabsf(dz0 + dc0) + fabsf(dz1 + dc1)) * v;
            const float vp = prow[36 + j];
            vv  += vp * v;
            sVp += vp * vp;
        }

        const float viz = sVp - 2.f * vv + sVg;   // sum (Vp - Vg)^2
        const float ctr = dc0 * dc0 + dc1 * dc1;

        const float c = -prob
                      + (0.5f * off + 4.0f * ab + 0.2f * viz + 0.5f * ctr) * nbinv;

        if (valid) out[p * T_TOT + t] = c;        // coalesced, t-contiguous
    }
}

extern "C" void kernel_launch(void* const* d_in, const int* in_sizes, int n_in,
                              void* d_out, int out_size, void* d_ws, size_t ws_size,
                              hipStream_t stream) {
    const float* logits    = (const float*)d_in[0];  // pred_logits    [8,500,2]
    const float* kp        = (const float*)d_in[1];  // pred_keypoints [8,500,53]
    const int*   tgt_ids   = (const int*)  d_in[2];  // [400]
    const float* tk        = (const float*)d_in[3];  // tgt_keypoints  [400,53]
    const int*   num_boxes = (const int*)  d_in[4];  // scalar
    float*       out       = (float*)d_out;          // [8,500,400] fp32

    hm_cost_kernel<<<P_TOT / PP, BD, 0, stream>>>(logits, kp, tgt_ids, tk,
                                                  num_boxes, out);
}